// Round 1
// baseline (966.795 us; speedup 1.0000x reference)
//
#include <hip/hip_runtime.h>

#define N_NODES 50000
#define N_EDGES 800000
#define FEAT    16
#define HID     128
#define NLAYERS 4
#define OUTD    12
#define NGRAPH  1024
#define SCAN_NB 196   // ceil((N_NODES+1)/256)

// ---------------- degree / dinv ----------------
__global__ void k_deg(const int* __restrict__ ei, int* __restrict__ degi) {
    int e = blockIdx.x * 256 + threadIdx.x;
    if (e < N_EDGES) atomicAdd(&degi[ei[N_EDGES + e]], 1);
}

__global__ void k_dinv(const int* __restrict__ degi, float* __restrict__ dinv) {
    int i = blockIdx.x * 256 + threadIdx.x;
    if (i < N_NODES) dinv[i] = rsqrtf((float)degi[i] + 1.0f);
}

// ---------------- 3-kernel exclusive scan over deg (N_NODES+1 elems) ----------------
__global__ void k_scan_part(const int* __restrict__ degi, int* __restrict__ part) {
    __shared__ int s[256];
    int t = threadIdx.x;
    int i = blockIdx.x * 256 + t;
    int v = (i < N_NODES) ? degi[i] : 0;
    s[t] = v;
    __syncthreads();
    for (int st = 128; st > 0; st >>= 1) {
        if (t < st) s[t] += s[t + st];
        __syncthreads();
    }
    if (t == 0) part[blockIdx.x] = s[0];
}

__global__ void k_scan_mid(int* __restrict__ part) {
    __shared__ int s[256];
    int t = threadIdx.x;
    int v = (t < SCAN_NB) ? part[t] : 0;
    s[t] = v;
    __syncthreads();
    for (int st = 1; st < 256; st <<= 1) {
        int u = (t >= st) ? s[t - st] : 0;
        __syncthreads();
        s[t] += u;
        __syncthreads();
    }
    if (t < SCAN_NB) part[t] = s[t] - v;   // exclusive
}

__global__ void k_scan_final(const int* __restrict__ degi, const int* __restrict__ part,
                             int* __restrict__ offs) {
    __shared__ int s[256];
    int t = threadIdx.x;
    int i = blockIdx.x * 256 + t;
    int v = (i < N_NODES) ? degi[i] : 0;
    s[t] = v;
    __syncthreads();
    for (int st = 1; st < 256; st <<= 1) {
        int u = (t >= st) ? s[t - st] : 0;
        __syncthreads();
        s[t] += u;
        __syncthreads();
    }
    if (i <= N_NODES) offs[i] = s[t] - v + part[blockIdx.x];
}

// ---------------- CSR fill ----------------
__global__ void k_fill(const int* __restrict__ ei, const int* __restrict__ offs,
                       int* __restrict__ cursor, int* __restrict__ csr) {
    int e = blockIdx.x * 256 + threadIdx.x;
    if (e < N_EDGES) {
        int srcv = ei[e];
        int dstv = ei[N_EDGES + e];
        int p = atomicAdd(&cursor[dstv], 1);
        csr[offs[dstv] + p] = srcv;
    }
}

// ---------------- node-embed MLP: h = relu(x@We1+be1)@We2+be2 ----------------
__global__ void __launch_bounds__(HID) k_embed(
        const float* __restrict__ x,
        const float* __restrict__ We1, const float* __restrict__ be1,
        const float* __restrict__ We2, const float* __restrict__ be2,
        float* __restrict__ h) {
    __shared__ float xr[FEAT];
    __shared__ float tl[HID];
    int n = blockIdx.x;
    int f = threadIdx.x;
    if (f < FEAT) xr[f] = x[n * FEAT + f];
    __syncthreads();
    float acc = be1[f];
#pragma unroll
    for (int k = 0; k < FEAT; ++k) acc += xr[k] * We1[k * HID + f];
    tl[f] = fmaxf(acc, 0.0f);
    __syncthreads();
    float acc2 = be2[f];
#pragma unroll 8
    for (int k = 0; k < HID; ++k) acc2 += tl[k] * We2[k * HID + f];
    h[n * HID + f] = acc2;
}

// ---------------- dense GEMM: B = A @ W, A [N,128], W [128,128] ----------------
#define GB_NODES 8
__global__ void __launch_bounds__(256) k_gemm(
        const float* __restrict__ A, const float* __restrict__ W,
        float* __restrict__ B) {
    __shared__ float a_l[GB_NODES][HID];
    int t  = threadIdx.x;
    int ln = t >> 5;             // 0..7
    int f4 = (t & 31) * 4;       // 0..124
    int n  = blockIdx.x * GB_NODES + ln;
    *(float4*)&a_l[ln][f4] = *(const float4*)&A[n * HID + f4];
    __syncthreads();
    float4 acc = make_float4(0.f, 0.f, 0.f, 0.f);
#pragma unroll 8
    for (int k = 0; k < HID; ++k) {
        float av = a_l[ln][k];
        float4 w = *(const float4*)&W[k * HID + f4];
        acc.x += av * w.x;
        acc.y += av * w.y;
        acc.z += av * w.z;
        acc.w += av * w.w;
    }
    *(float4*)&B[n * HID + f4] = acc;
}

// ---------------- CSR aggregation + self-loop + bias + relu ----------------
__global__ void __launch_bounds__(HID) k_agg(
        const float* __restrict__ hp,       // h' = h @ W
        const int* __restrict__ csr, const int* __restrict__ offs,
        const float* __restrict__ dinv, const float* __restrict__ bias,
        float* __restrict__ hout) {
    __shared__ int   s_src[HID];
    __shared__ float s_nm[HID];
    int i = blockIdx.x;
    int f = threadIdx.x;
    float di = dinv[i];
    int s0 = offs[i], s1 = offs[i + 1];
    float acc = hp[i * HID + f] * (di * di) + bias[f];
    for (int base = s0; base < s1; base += HID) {
        int cnt = min(HID, s1 - base);
        if (f < cnt) {
            int sv = csr[base + f];
            s_src[f] = sv;
            s_nm[f]  = di * dinv[sv];
        }
        __syncthreads();
#pragma unroll 4
        for (int j = 0; j < cnt; ++j)
            acc += hp[s_src[j] * HID + f] * s_nm[j];
        __syncthreads();
    }
    hout[i * HID + f] = fmaxf(acc, 0.0f);
}

// ---------------- pooling (segment sum via atomics) ----------------
__global__ void __launch_bounds__(HID) k_pool(
        const float* __restrict__ h, const int* __restrict__ batch,
        float* __restrict__ pooled, float* __restrict__ cnt) {
    int n = blockIdx.x;
    int f = threadIdx.x;
    int g = batch[n];
    atomicAdd(&pooled[g * HID + f], h[n * HID + f]);
    if (f == 0) atomicAdd(&cnt[g], 1.0f);
}

// ---------------- output head: out = (pooled/cnt) @ Wo + bo ----------------
__global__ void __launch_bounds__(HID) k_out(
        const float* __restrict__ pooled, const float* __restrict__ cnt,
        const float* __restrict__ Wo, const float* __restrict__ bo,
        float* __restrict__ out) {
    __shared__ float p[HID];
    int g = blockIdx.x;
    int f = threadIdx.x;
    float inv = 1.0f / fmaxf(cnt[g], 1.0f);
    p[f] = pooled[g * HID + f] * inv;
    __syncthreads();
    if (f < OUTD) {
        float acc = bo[f];
#pragma unroll 8
        for (int k = 0; k < HID; ++k) acc += p[k] * Wo[k * OUTD + f];
        out[g * OUTD + f] = acc;
    }
}

extern "C" void kernel_launch(void* const* d_in, const int* in_sizes, int n_in,
                              void* d_out, int out_size, void* d_ws, size_t ws_size,
                              hipStream_t stream) {
    const float* x    = (const float*)d_in[0];
    const int*   ei   = (const int*)d_in[1];
    // d_in[2] edge_attr unused
    const int*   bidx = (const int*)d_in[3];
    const float* We1  = (const float*)d_in[4];
    const float* be1  = (const float*)d_in[5];
    const float* We2  = (const float*)d_in[6];
    const float* be2  = (const float*)d_in[7];
    const float* Wg   = (const float*)d_in[8];
    const float* bg   = (const float*)d_in[9];
    const float* Wo   = (const float*)d_in[10];
    const float* bo   = (const float*)d_in[11];
    float* out = (float*)d_out;

    // ---- workspace layout (256B aligned) ----
    char* ws = (char*)d_ws;
    size_t o = 0;
    auto take = [&](size_t bytes) { size_t r = o; o += (bytes + 255) & ~(size_t)255; return r; };
    size_t off_degi   = take((size_t)N_NODES * 4);
    size_t off_cursor = take((size_t)N_NODES * 4);
    size_t off_pooled = take((size_t)NGRAPH * HID * 4);
    size_t off_cnt    = take((size_t)NGRAPH * 4);
    size_t zero_bytes = o;                       // [0, o) gets memset to 0
    size_t off_dinv   = take((size_t)N_NODES * 4);
    size_t off_offs   = take((size_t)(N_NODES + 1) * 4);
    size_t off_part   = take((size_t)256 * 4);
    size_t off_csr    = take((size_t)N_EDGES * 4);
    size_t off_hA     = take((size_t)N_NODES * HID * 4);
    size_t off_hB     = take((size_t)N_NODES * HID * 4);

    int*   degi   = (int*)(ws + off_degi);
    int*   cursor = (int*)(ws + off_cursor);
    float* pooled = (float*)(ws + off_pooled);
    float* cnt    = (float*)(ws + off_cnt);
    float* dinv   = (float*)(ws + off_dinv);
    int*   offs   = (int*)(ws + off_offs);
    int*   part   = (int*)(ws + off_part);
    int*   csr    = (int*)(ws + off_csr);
    float* hA     = (float*)(ws + off_hA);
    float* hB     = (float*)(ws + off_hB);

    hipMemsetAsync(d_ws, 0, zero_bytes, stream);

    // degree + dinv + CSR build (amortized across 4 layers)
    k_deg<<<(N_EDGES + 255) / 256, 256, 0, stream>>>(ei, degi);
    k_dinv<<<(N_NODES + 255) / 256, 256, 0, stream>>>(degi, dinv);
    k_scan_part<<<SCAN_NB, 256, 0, stream>>>(degi, part);
    k_scan_mid<<<1, 256, 0, stream>>>(part);
    k_scan_final<<<SCAN_NB, 256, 0, stream>>>(degi, part, offs);
    k_fill<<<(N_EDGES + 255) / 256, 256, 0, stream>>>(ei, offs, cursor, csr);

    // node embedding MLP
    k_embed<<<N_NODES, HID, 0, stream>>>(x, We1, be1, We2, be2, hA);

    // 4 GCN layers: hB = hA @ Wg[l];  hA = relu(agg(hB) + self + bias)
    for (int l = 0; l < NLAYERS; ++l) {
        k_gemm<<<N_NODES / GB_NODES, 256, 0, stream>>>(hA, Wg + (size_t)l * HID * HID, hB);
        k_agg<<<N_NODES, HID, 0, stream>>>(hB, csr, offs, dinv, bg + (size_t)l * HID, hA);
    }

    // pooling + output head
    k_pool<<<N_NODES, HID, 0, stream>>>(hA, bidx, pooled, cnt);
    k_out<<<NGRAPH, HID, 0, stream>>>(pooled, cnt, Wo, bo, out);
}

// Round 2
// 647.315 us; speedup vs baseline: 1.4935x; 1.4935x over previous
//
#include <hip/hip_runtime.h>

#define N_NODES 50000
#define N_EDGES 800000
#define FEAT    16
#define HID     128
#define NLAYERS 4
#define OUTD    12
#define NGRAPH  1024
#define SCAN_NB 196   // ceil((N_NODES+1)/256)

__device__ inline float4 f4zero() { return make_float4(0.f, 0.f, 0.f, 0.f); }
__device__ inline float4 f4fma(float a, float4 w, float4 acc) {
    acc.x = fmaf(a, w.x, acc.x);
    acc.y = fmaf(a, w.y, acc.y);
    acc.z = fmaf(a, w.z, acc.z);
    acc.w = fmaf(a, w.w, acc.w);
    return acc;
}
__device__ inline float4 f4add(float4 a, float4 b) {
    return make_float4(a.x + b.x, a.y + b.y, a.z + b.z, a.w + b.w);
}

// ---------------- degree / dinv ----------------
__global__ void k_deg(const int* __restrict__ ei, int* __restrict__ degi) {
    int e = blockIdx.x * 256 + threadIdx.x;
    if (e < N_EDGES) atomicAdd(&degi[ei[N_EDGES + e]], 1);
}

__global__ void k_dinv(const int* __restrict__ degi, float* __restrict__ dinv) {
    int i = blockIdx.x * 256 + threadIdx.x;
    if (i < N_NODES) dinv[i] = rsqrtf((float)degi[i] + 1.0f);
}

// ---------------- 3-kernel exclusive scan over deg (N_NODES+1 elems) ----------------
__global__ void k_scan_part(const int* __restrict__ degi, int* __restrict__ part) {
    __shared__ int s[256];
    int t = threadIdx.x;
    int i = blockIdx.x * 256 + t;
    int v = (i < N_NODES) ? degi[i] : 0;
    s[t] = v;
    __syncthreads();
    for (int st = 128; st > 0; st >>= 1) {
        if (t < st) s[t] += s[t + st];
        __syncthreads();
    }
    if (t == 0) part[blockIdx.x] = s[0];
}

__global__ void k_scan_mid(int* __restrict__ part) {
    __shared__ int s[256];
    int t = threadIdx.x;
    int v = (t < SCAN_NB) ? part[t] : 0;
    s[t] = v;
    __syncthreads();
    for (int st = 1; st < 256; st <<= 1) {
        int u = (t >= st) ? s[t - st] : 0;
        __syncthreads();
        s[t] += u;
        __syncthreads();
    }
    if (t < SCAN_NB) part[t] = s[t] - v;   // exclusive
}

__global__ void k_scan_final(const int* __restrict__ degi, const int* __restrict__ part,
                             int* __restrict__ offs) {
    __shared__ int s[256];
    int t = threadIdx.x;
    int i = blockIdx.x * 256 + t;
    int v = (i < N_NODES) ? degi[i] : 0;
    s[t] = v;
    __syncthreads();
    for (int st = 1; st < 256; st <<= 1) {
        int u = (t >= st) ? s[t - st] : 0;
        __syncthreads();
        s[t] += u;
        __syncthreads();
    }
    if (i <= N_NODES) offs[i] = s[t] - v + part[blockIdx.x];
}

// ---------------- CSR fill (also stores dinv[src] per slot to break the
// dependent csr[j] -> dinv[sv] load chain in k_agg) ----------------
__global__ void k_fill(const int* __restrict__ ei, const int* __restrict__ offs,
                       const float* __restrict__ dinv,
                       int* __restrict__ cursor, int* __restrict__ csr,
                       float* __restrict__ csrnm) {
    int e = blockIdx.x * 256 + threadIdx.x;
    if (e < N_EDGES) {
        int srcv = ei[e];
        int dstv = ei[N_EDGES + e];
        int p = atomicAdd(&cursor[dstv], 1);
        int slot = offs[dstv] + p;
        csr[slot]   = srcv;
        csrnm[slot] = dinv[srcv];
    }
}

// ---------------- embed stage 1: t = relu(x @ We1 + be1), K=16 ----------------
#define GM 32
__global__ void __launch_bounds__(256) k_embed1(
        const float* __restrict__ x,
        const float* __restrict__ W1, const float* __restrict__ b1,
        float* __restrict__ t_out) {
    __shared__ float x_l[GM][FEAT];
    int t = threadIdx.x;
    long n0 = (long)blockIdx.x * GM;
    // cooperative load 32x16 floats = 128 float4 (threads 0..127)
    if (t < 128) {
        int r  = t >> 2;
        int c4 = (t & 3) << 2;
        long n = n0 + r;
        float4 v = (n < N_NODES) ? *(const float4*)&x[n * FEAT + c4] : f4zero();
        *(float4*)&x_l[r][c4] = v;
    }
    __syncthreads();
    int fgrp = t & 31, ngrp = t >> 5;
    int f4 = fgrp << 2;
    float4 acc0 = f4zero(), acc1 = f4zero(), acc2 = f4zero(), acc3 = f4zero();
#pragma unroll
    for (int k = 0; k < FEAT; ++k) {
        float4 w = *(const float4*)&W1[k * HID + f4];
        acc0 = f4fma(x_l[ngrp * 4 + 0][k], w, acc0);
        acc1 = f4fma(x_l[ngrp * 4 + 1][k], w, acc1);
        acc2 = f4fma(x_l[ngrp * 4 + 2][k], w, acc2);
        acc3 = f4fma(x_l[ngrp * 4 + 3][k], w, acc3);
    }
    float4 bv = *(const float4*)&b1[f4];
    acc0 = f4add(acc0, bv); acc1 = f4add(acc1, bv);
    acc2 = f4add(acc2, bv); acc3 = f4add(acc3, bv);
    acc0.x = fmaxf(acc0.x, 0.f); acc0.y = fmaxf(acc0.y, 0.f); acc0.z = fmaxf(acc0.z, 0.f); acc0.w = fmaxf(acc0.w, 0.f);
    acc1.x = fmaxf(acc1.x, 0.f); acc1.y = fmaxf(acc1.y, 0.f); acc1.z = fmaxf(acc1.z, 0.f); acc1.w = fmaxf(acc1.w, 0.f);
    acc2.x = fmaxf(acc2.x, 0.f); acc2.y = fmaxf(acc2.y, 0.f); acc2.z = fmaxf(acc2.z, 0.f); acc2.w = fmaxf(acc2.w, 0.f);
    acc3.x = fmaxf(acc3.x, 0.f); acc3.y = fmaxf(acc3.y, 0.f); acc3.z = fmaxf(acc3.z, 0.f); acc3.w = fmaxf(acc3.w, 0.f);
    long n;
    n = n0 + ngrp * 4 + 0; if (n < N_NODES) *(float4*)&t_out[n * HID + f4] = acc0;
    n = n0 + ngrp * 4 + 1; if (n < N_NODES) *(float4*)&t_out[n * HID + f4] = acc1;
    n = n0 + ngrp * 4 + 2; if (n < N_NODES) *(float4*)&t_out[n * HID + f4] = acc2;
    n = n0 + ngrp * 4 + 3; if (n < N_NODES) *(float4*)&t_out[n * HID + f4] = acc3;
}

// ---------------- dense GEMM: B = A @ W (+bias), A [N,128], W [128,128] ----------------
// M=32 nodes/block, 256 threads, 4 nodes per thread (float4 accs).
__global__ void __launch_bounds__(256) k_gemm(
        const float* __restrict__ A, const float* __restrict__ W,
        const float* __restrict__ bias, float* __restrict__ B) {
    __shared__ float a_l[GM][HID];
    int t = threadIdx.x;
    long n0 = (long)blockIdx.x * GM;
    // cooperative load 32x128 floats = 1024 float4, 4 per thread
#pragma unroll
    for (int i = 0; i < 4; ++i) {
        int p  = t + 256 * i;
        int r  = p >> 5;
        int c4 = (p & 31) << 2;
        long n = n0 + r;
        float4 v = (n < N_NODES) ? *(const float4*)&A[n * HID + c4] : f4zero();
        *(float4*)&a_l[r][c4] = v;
    }
    __syncthreads();
    int fgrp = t & 31, ngrp = t >> 5;
    int f4 = fgrp << 2;
    float4 acc0 = f4zero(), acc1 = f4zero(), acc2 = f4zero(), acc3 = f4zero();
#pragma unroll 8
    for (int k = 0; k < HID; ++k) {
        float4 w = *(const float4*)&W[k * HID + f4];
        acc0 = f4fma(a_l[ngrp * 4 + 0][k], w, acc0);
        acc1 = f4fma(a_l[ngrp * 4 + 1][k], w, acc1);
        acc2 = f4fma(a_l[ngrp * 4 + 2][k], w, acc2);
        acc3 = f4fma(a_l[ngrp * 4 + 3][k], w, acc3);
    }
    if (bias) {
        float4 bv = *(const float4*)&bias[f4];
        acc0 = f4add(acc0, bv); acc1 = f4add(acc1, bv);
        acc2 = f4add(acc2, bv); acc3 = f4add(acc3, bv);
    }
    long n;
    n = n0 + ngrp * 4 + 0; if (n < N_NODES) *(float4*)&B[n * HID + f4] = acc0;
    n = n0 + ngrp * 4 + 1; if (n < N_NODES) *(float4*)&B[n * HID + f4] = acc1;
    n = n0 + ngrp * 4 + 2; if (n < N_NODES) *(float4*)&B[n * HID + f4] = acc2;
    n = n0 + ngrp * 4 + 3; if (n < N_NODES) *(float4*)&B[n * HID + f4] = acc3;
}

// ---------------- CSR aggregation + self-loop + bias + relu ----------------
// One 32-lane group per dst node; lane owns 4 features (float4).
__global__ void __launch_bounds__(256) k_agg(
        const float* __restrict__ hp,       // h' = h @ W
        const int* __restrict__ csr, const float* __restrict__ csrnm,
        const int* __restrict__ offs,
        const float* __restrict__ dinv, const float* __restrict__ bias,
        float* __restrict__ hout) {
    int t = threadIdx.x;
    int lane = t & 31, grp = t >> 5;
    int i = blockIdx.x * 8 + grp;
    if (i >= N_NODES) return;
    float di = dinv[i];
    int s0 = offs[i], s1 = offs[i + 1];
    const float4* hp4 = (const float4*)hp;
    float4 self = hp4[(long)i * 32 + lane];
    float4 acc  = *(const float4*)&bias[lane << 2];
    acc = f4fma(di * di, self, acc);
    for (int j = s0; j < s1; ++j) {
        int   sv = csr[j];       // broadcast load (uniform in group)
        float nm = di * csrnm[j]; // independent broadcast load
        float4 v = hp4[(long)sv * 32 + lane];
        acc = f4fma(nm, v, acc);
    }
    acc.x = fmaxf(acc.x, 0.f); acc.y = fmaxf(acc.y, 0.f);
    acc.z = fmaxf(acc.z, 0.f); acc.w = fmaxf(acc.w, 0.f);
    ((float4*)hout)[(long)i * 32 + lane] = acc;
}

// ---------------- pooling: sorted-batch run-length accumulation ----------------
#define PN 16
__global__ void __launch_bounds__(256) k_pool(
        const float* __restrict__ h, const int* __restrict__ batch,
        float* __restrict__ pooled, float* __restrict__ cnt) {
    int t = threadIdx.x;
    int lane = t & 31, grp = t >> 5;
    long n0 = ((long)blockIdx.x * 8 + grp) * PN;
    if (n0 >= N_NODES) return;
    long n1 = n0 + PN; if (n1 > N_NODES) n1 = N_NODES;
    const float4* h4 = (const float4*)h;
    float4 run = f4zero();
    int curg = batch[n0];
    int c = 0;
    for (long n = n0; n < n1; ++n) {
        int g = batch[n];
        if (g != curg) {
            float* pb = &pooled[(long)curg * HID + (lane << 2)];
            atomicAdd(pb + 0, run.x); atomicAdd(pb + 1, run.y);
            atomicAdd(pb + 2, run.z); atomicAdd(pb + 3, run.w);
            if (lane == 0) atomicAdd(&cnt[curg], (float)c);
            run = f4zero(); c = 0; curg = g;
        }
        run = f4add(run, h4[n * 32 + lane]);
        ++c;
    }
    float* pb = &pooled[(long)curg * HID + (lane << 2)];
    atomicAdd(pb + 0, run.x); atomicAdd(pb + 1, run.y);
    atomicAdd(pb + 2, run.z); atomicAdd(pb + 3, run.w);
    if (lane == 0) atomicAdd(&cnt[curg], (float)c);
}

// ---------------- output head: out = (pooled/cnt) @ Wo + bo ----------------
__global__ void __launch_bounds__(HID) k_out(
        const float* __restrict__ pooled, const float* __restrict__ cnt,
        const float* __restrict__ Wo, const float* __restrict__ bo,
        float* __restrict__ out) {
    __shared__ float p[HID];
    int g = blockIdx.x;
    int f = threadIdx.x;
    float inv = 1.0f / fmaxf(cnt[g], 1.0f);
    p[f] = pooled[g * HID + f] * inv;
    __syncthreads();
    if (f < OUTD) {
        float acc = bo[f];
#pragma unroll 8
        for (int k = 0; k < HID; ++k) acc += p[k] * Wo[k * OUTD + f];
        out[g * OUTD + f] = acc;
    }
}

extern "C" void kernel_launch(void* const* d_in, const int* in_sizes, int n_in,
                              void* d_out, int out_size, void* d_ws, size_t ws_size,
                              hipStream_t stream) {
    const float* x    = (const float*)d_in[0];
    const int*   ei   = (const int*)d_in[1];
    // d_in[2] edge_attr unused
    const int*   bidx = (const int*)d_in[3];
    const float* We1  = (const float*)d_in[4];
    const float* be1  = (const float*)d_in[5];
    const float* We2  = (const float*)d_in[6];
    const float* be2  = (const float*)d_in[7];
    const float* Wg   = (const float*)d_in[8];
    const float* bg   = (const float*)d_in[9];
    const float* Wo   = (const float*)d_in[10];
    const float* bo   = (const float*)d_in[11];
    float* out = (float*)d_out;

    // ---- workspace layout (256B aligned) ----
    char* ws = (char*)d_ws;
    size_t o = 0;
    auto take = [&](size_t bytes) { size_t r = o; o += (bytes + 255) & ~(size_t)255; return r; };
    size_t off_degi   = take((size_t)N_NODES * 4);
    size_t off_cursor = take((size_t)N_NODES * 4);
    size_t off_pooled = take((size_t)NGRAPH * HID * 4);
    size_t off_cnt    = take((size_t)NGRAPH * 4);
    size_t zero_bytes = o;                       // [0, o) gets memset to 0
    size_t off_dinv   = take((size_t)N_NODES * 4);
    size_t off_offs   = take((size_t)(N_NODES + 1) * 4);
    size_t off_part   = take((size_t)256 * 4);
    size_t off_csr    = take((size_t)N_EDGES * 4);
    size_t off_csrnm  = take((size_t)N_EDGES * 4);
    size_t off_hA     = take((size_t)N_NODES * HID * 4);
    size_t off_hB     = take((size_t)N_NODES * HID * 4);

    int*   degi   = (int*)(ws + off_degi);
    int*   cursor = (int*)(ws + off_cursor);
    float* pooled = (float*)(ws + off_pooled);
    float* cnt    = (float*)(ws + off_cnt);
    float* dinv   = (float*)(ws + off_dinv);
    int*   offs   = (int*)(ws + off_offs);
    int*   part   = (int*)(ws + off_part);
    int*   csr    = (int*)(ws + off_csr);
    float* csrnm  = (float*)(ws + off_csrnm);
    float* hA     = (float*)(ws + off_hA);
    float* hB     = (float*)(ws + off_hB);

    hipMemsetAsync(d_ws, 0, zero_bytes, stream);

    // degree + dinv + CSR build (amortized across 4 layers)
    k_deg<<<(N_EDGES + 255) / 256, 256, 0, stream>>>(ei, degi);
    k_dinv<<<(N_NODES + 255) / 256, 256, 0, stream>>>(degi, dinv);
    k_scan_part<<<SCAN_NB, 256, 0, stream>>>(degi, part);
    k_scan_mid<<<1, 256, 0, stream>>>(part);
    k_scan_final<<<SCAN_NB, 256, 0, stream>>>(degi, part, offs);
    k_fill<<<(N_EDGES + 255) / 256, 256, 0, stream>>>(ei, offs, dinv, cursor, csr, csrnm);

    // node embedding MLP: hB = relu(x@We1+be1); hA = hB@We2+be2
    int gemm_grid = (N_NODES + GM - 1) / GM;
    k_embed1<<<gemm_grid, 256, 0, stream>>>(x, We1, be1, hB);
    k_gemm<<<gemm_grid, 256, 0, stream>>>(hB, We2, be2, hA);

    // 4 GCN layers: hB = hA @ Wg[l];  hA = relu(agg(hB) + self + bias)
    for (int l = 0; l < NLAYERS; ++l) {
        k_gemm<<<gemm_grid, 256, 0, stream>>>(hA, Wg + (size_t)l * HID * HID, nullptr, hB);
        k_agg<<<(N_NODES + 7) / 8, 256, 0, stream>>>(hB, csr, csrnm, offs, dinv,
                                                     bg + (size_t)l * HID, hA);
    }

    // pooling + output head
    k_pool<<<(N_NODES + 8 * PN - 1) / (8 * PN), 256, 0, stream>>>(hA, bidx, pooled, cnt);
    k_out<<<NGRAPH, HID, 0, stream>>>(pooled, cnt, Wo, bo, out);
}

// Round 3
// 594.366 us; speedup vs baseline: 1.6266x; 1.0891x over previous
//
#include <hip/hip_runtime.h>

#define N_NODES 50000
#define N_EDGES 800000
#define FEAT    16
#define HID     128
#define NLAYERS 4
#define OUTD    12
#define NGRAPH  1024
#define SCAN_NB 196   // ceil((N_NODES+1)/256)

__device__ inline float4 f4zero() { return make_float4(0.f, 0.f, 0.f, 0.f); }
__device__ inline float4 f4fma(float a, float4 w, float4 acc) {
    acc.x = fmaf(a, w.x, acc.x);
    acc.y = fmaf(a, w.y, acc.y);
    acc.z = fmaf(a, w.z, acc.z);
    acc.w = fmaf(a, w.w, acc.w);
    return acc;
}
__device__ inline float4 f4add(float4 a, float4 b) {
    return make_float4(a.x + b.x, a.y + b.y, a.z + b.z, a.w + b.w);
}

// ---------------- degree / dinv ----------------
__global__ void k_deg(const int* __restrict__ ei, int* __restrict__ degi) {
    int e = blockIdx.x * 256 + threadIdx.x;
    if (e < N_EDGES) atomicAdd(&degi[ei[N_EDGES + e]], 1);
}

__global__ void k_dinv(const int* __restrict__ degi, float* __restrict__ dinv) {
    int i = blockIdx.x * 256 + threadIdx.x;
    if (i < N_NODES) dinv[i] = rsqrtf((float)degi[i] + 1.0f);
}

// ---------------- 3-kernel exclusive scan over deg (N_NODES+1 elems) ----------------
__global__ void k_scan_part(const int* __restrict__ degi, int* __restrict__ part) {
    __shared__ int s[256];
    int t = threadIdx.x;
    int i = blockIdx.x * 256 + t;
    int v = (i < N_NODES) ? degi[i] : 0;
    s[t] = v;
    __syncthreads();
    for (int st = 128; st > 0; st >>= 1) {
        if (t < st) s[t] += s[t + st];
        __syncthreads();
    }
    if (t == 0) part[blockIdx.x] = s[0];
}

__global__ void k_scan_mid(int* __restrict__ part) {
    __shared__ int s[256];
    int t = threadIdx.x;
    int v = (t < SCAN_NB) ? part[t] : 0;
    s[t] = v;
    __syncthreads();
    for (int st = 1; st < 256; st <<= 1) {
        int u = (t >= st) ? s[t - st] : 0;
        __syncthreads();
        s[t] += u;
        __syncthreads();
    }
    if (t < SCAN_NB) part[t] = s[t] - v;   // exclusive
}

__global__ void k_scan_final(const int* __restrict__ degi, const int* __restrict__ part,
                             int* __restrict__ offs) {
    __shared__ int s[256];
    int t = threadIdx.x;
    int i = blockIdx.x * 256 + t;
    int v = (i < N_NODES) ? degi[i] : 0;
    s[t] = v;
    __syncthreads();
    for (int st = 1; st < 256; st <<= 1) {
        int u = (t >= st) ? s[t - st] : 0;
        __syncthreads();
        s[t] += u;
        __syncthreads();
    }
    if (i <= N_NODES) offs[i] = s[t] - v + part[blockIdx.x];
}

// ---------------- CSR fill (stores dinv[src] per slot too) ----------------
__global__ void k_fill(const int* __restrict__ ei, const int* __restrict__ offs,
                       const float* __restrict__ dinv,
                       int* __restrict__ cursor, int* __restrict__ csr,
                       float* __restrict__ csrnm) {
    int e = blockIdx.x * 256 + threadIdx.x;
    if (e < N_EDGES) {
        int srcv = ei[e];
        int dstv = ei[N_EDGES + e];
        int p = atomicAdd(&cursor[dstv], 1);
        int slot = offs[dstv] + p;
        csr[slot]   = srcv;
        csrnm[slot] = dinv[srcv];
    }
}

// ---------------- embed stage 1: t = relu(x @ We1 + be1), K=16 ----------------
#define EM 32
__global__ void __launch_bounds__(256) k_embed1(
        const float* __restrict__ x,
        const float* __restrict__ W1, const float* __restrict__ b1,
        float* __restrict__ t_out) {
    __shared__ float x_l[EM][FEAT];
    int t = threadIdx.x;
    long n0 = (long)blockIdx.x * EM;
    if (t < 128) {
        int r  = t >> 2;
        int c4 = (t & 3) << 2;
        long n = n0 + r;
        float4 v = (n < N_NODES) ? *(const float4*)&x[n * FEAT + c4] : f4zero();
        *(float4*)&x_l[r][c4] = v;
    }
    __syncthreads();
    int fgrp = t & 31, ngrp = t >> 5;
    int f4 = fgrp << 2;
    float4 acc0 = f4zero(), acc1 = f4zero(), acc2 = f4zero(), acc3 = f4zero();
#pragma unroll
    for (int k = 0; k < FEAT; ++k) {
        float4 w = *(const float4*)&W1[k * HID + f4];
        acc0 = f4fma(x_l[ngrp * 4 + 0][k], w, acc0);
        acc1 = f4fma(x_l[ngrp * 4 + 1][k], w, acc1);
        acc2 = f4fma(x_l[ngrp * 4 + 2][k], w, acc2);
        acc3 = f4fma(x_l[ngrp * 4 + 3][k], w, acc3);
    }
    float4 bv = *(const float4*)&b1[f4];
    acc0 = f4add(acc0, bv); acc1 = f4add(acc1, bv);
    acc2 = f4add(acc2, bv); acc3 = f4add(acc3, bv);
    acc0.x = fmaxf(acc0.x, 0.f); acc0.y = fmaxf(acc0.y, 0.f); acc0.z = fmaxf(acc0.z, 0.f); acc0.w = fmaxf(acc0.w, 0.f);
    acc1.x = fmaxf(acc1.x, 0.f); acc1.y = fmaxf(acc1.y, 0.f); acc1.z = fmaxf(acc1.z, 0.f); acc1.w = fmaxf(acc1.w, 0.f);
    acc2.x = fmaxf(acc2.x, 0.f); acc2.y = fmaxf(acc2.y, 0.f); acc2.z = fmaxf(acc2.z, 0.f); acc2.w = fmaxf(acc2.w, 0.f);
    acc3.x = fmaxf(acc3.x, 0.f); acc3.y = fmaxf(acc3.y, 0.f); acc3.z = fmaxf(acc3.z, 0.f); acc3.w = fmaxf(acc3.w, 0.f);
    long n;
    n = n0 + ngrp * 4 + 0; if (n < N_NODES) *(float4*)&t_out[n * HID + f4] = acc0;
    n = n0 + ngrp * 4 + 1; if (n < N_NODES) *(float4*)&t_out[n * HID + f4] = acc1;
    n = n0 + ngrp * 4 + 2; if (n < N_NODES) *(float4*)&t_out[n * HID + f4] = acc2;
    n = n0 + ngrp * 4 + 3; if (n < N_NODES) *(float4*)&t_out[n * HID + f4] = acc3;
}

// ---------------- dense GEMM: B = A @ W (+bias), A [N,128], W [128,128] ----------------
// M=64 nodes/block, 256 threads, 8 nodes per thread (float4 accs).
#define GM 64
__global__ void __launch_bounds__(256) k_gemm(
        const float* __restrict__ A, const float* __restrict__ W,
        const float* __restrict__ bias, float* __restrict__ B) {
    __shared__ float a_l[GM][HID];
    int t = threadIdx.x;
    long n0 = (long)blockIdx.x * GM;
    // cooperative load 64x128 floats = 2048 float4, 8 per thread
#pragma unroll
    for (int i = 0; i < 8; ++i) {
        int p  = t + 256 * i;
        int r  = p >> 5;
        int c4 = (p & 31) << 2;
        long n = n0 + r;
        float4 v = (n < N_NODES) ? *(const float4*)&A[n * HID + c4] : f4zero();
        *(float4*)&a_l[r][c4] = v;
    }
    __syncthreads();
    int fgrp = t & 31, ngrp = t >> 5;   // ngrp owns rows ngrp*8 .. ngrp*8+7
    int f4 = fgrp << 2;
    float4 acc[8];
#pragma unroll
    for (int r = 0; r < 8; ++r) acc[r] = f4zero();
#pragma unroll 8
    for (int k = 0; k < HID; ++k) {
        float4 w = *(const float4*)&W[k * HID + f4];
#pragma unroll
        for (int r = 0; r < 8; ++r)
            acc[r] = f4fma(a_l[ngrp * 8 + r][k], w, acc[r]);
    }
    if (bias) {
        float4 bv = *(const float4*)&bias[f4];
#pragma unroll
        for (int r = 0; r < 8; ++r) acc[r] = f4add(acc[r], bv);
    }
#pragma unroll
    for (int r = 0; r < 8; ++r) {
        long n = n0 + ngrp * 8 + r;
        if (n < N_NODES) *(float4*)&B[n * HID + f4] = acc[r];
    }
}

// ---------------- CSR aggregation + self-loop + bias + relu ----------------
// One wave (64 lanes) per dst node; lane owns 2 features (float2).
// Edge indices staged per-lane, broadcast via shfl -> 8 independent gathers in flight.
__global__ void __launch_bounds__(256) k_agg(
        const float* __restrict__ hp,       // h' = h @ W
        const int* __restrict__ csr, const float* __restrict__ csrnm,
        const int* __restrict__ offs,
        const float* __restrict__ dinv, const float* __restrict__ bias,
        float* __restrict__ hout) {
    int t = threadIdx.x;
    int lane = t & 63;
    int w = t >> 6;                       // wave 0..3
    int i = blockIdx.x * 4 + w;
    if (i >= N_NODES) return;
    float di = dinv[i];
    int s0 = offs[i], s1 = offs[i + 1];
    const float2* hp2 = (const float2*)hp;
    float2 self = hp2[(long)i * 64 + lane];
    float2 bv = ((const float2*)bias)[lane];
    float ax = fmaf(di * di, self.x, bv.x);
    float ay = fmaf(di * di, self.y, bv.y);
    for (int base = s0; base < s1; base += 64) {
        int n = s1 - base; if (n > 64) n = 64;
        int last = n - 1;
        int idx = base + lane;
        int   sv_l = (lane < n) ? csr[idx]        : 0;
        float nm_l = (lane < n) ? csrnm[idx] * di : 0.f;  // OOB lanes carry 0
        for (int k = 0; k < n; k += 8) {
            int a[8]; float m[8];
#pragma unroll
            for (int u = 0; u < 8; ++u) {
                int kk = k + u;
                int ks = kk < last ? kk : last;   // clamp (dup of last real edge)
                a[u] = __shfl(sv_l, ks);
                float mu = __shfl(nm_l, ks);
                m[u] = (kk < n) ? mu : 0.f;
            }
            float2 v[8];
#pragma unroll
            for (int u = 0; u < 8; ++u) v[u] = hp2[(long)a[u] * 64 + lane];
#pragma unroll
            for (int u = 0; u < 8; ++u) {
                ax = fmaf(m[u], v[u].x, ax);
                ay = fmaf(m[u], v[u].y, ay);
            }
        }
    }
    float2 r;
    r.x = fmaxf(ax, 0.f);
    r.y = fmaxf(ay, 0.f);
    ((float2*)hout)[(long)i * 64 + lane] = r;
}

// ---------------- pooling: sorted-batch run-length accumulation ----------------
#define PN 16
__global__ void __launch_bounds__(256) k_pool(
        const float* __restrict__ h, const int* __restrict__ batch,
        float* __restrict__ pooled, float* __restrict__ cnt) {
    int t = threadIdx.x;
    int lane = t & 31, grp = t >> 5;
    long n0 = ((long)blockIdx.x * 8 + grp) * PN;
    if (n0 >= N_NODES) return;
    long n1 = n0 + PN; if (n1 > N_NODES) n1 = N_NODES;
    const float4* h4 = (const float4*)h;
    float4 run = f4zero();
    int curg = batch[n0];
    int c = 0;
    for (long n = n0; n < n1; ++n) {
        int g = batch[n];
        if (g != curg) {
            float* pb = &pooled[(long)curg * HID + (lane << 2)];
            atomicAdd(pb + 0, run.x); atomicAdd(pb + 1, run.y);
            atomicAdd(pb + 2, run.z); atomicAdd(pb + 3, run.w);
            if (lane == 0) atomicAdd(&cnt[curg], (float)c);
            run = f4zero(); c = 0; curg = g;
        }
        run = f4add(run, h4[n * 32 + lane]);
        ++c;
    }
    float* pb = &pooled[(long)curg * HID + (lane << 2)];
    atomicAdd(pb + 0, run.x); atomicAdd(pb + 1, run.y);
    atomicAdd(pb + 2, run.z); atomicAdd(pb + 3, run.w);
    if (lane == 0) atomicAdd(&cnt[curg], (float)c);
}

// ---------------- output head: out = (pooled/cnt) @ Wo + bo ----------------
__global__ void __launch_bounds__(HID) k_out(
        const float* __restrict__ pooled, const float* __restrict__ cnt,
        const float* __restrict__ Wo, const float* __restrict__ bo,
        float* __restrict__ out) {
    __shared__ float p[HID];
    int g = blockIdx.x;
    int f = threadIdx.x;
    float inv = 1.0f / fmaxf(cnt[g], 1.0f);
    p[f] = pooled[g * HID + f] * inv;
    __syncthreads();
    if (f < OUTD) {
        float acc = bo[f];
#pragma unroll 8
        for (int k = 0; k < HID; ++k) acc += p[k] * Wo[k * OUTD + f];
        out[g * OUTD + f] = acc;
    }
}

extern "C" void kernel_launch(void* const* d_in, const int* in_sizes, int n_in,
                              void* d_out, int out_size, void* d_ws, size_t ws_size,
                              hipStream_t stream) {
    const float* x    = (const float*)d_in[0];
    const int*   ei   = (const int*)d_in[1];
    // d_in[2] edge_attr unused
    const int*   bidx = (const int*)d_in[3];
    const float* We1  = (const float*)d_in[4];
    const float* be1  = (const float*)d_in[5];
    const float* We2  = (const float*)d_in[6];
    const float* be2  = (const float*)d_in[7];
    const float* Wg   = (const float*)d_in[8];
    const float* bg   = (const float*)d_in[9];
    const float* Wo   = (const float*)d_in[10];
    const float* bo   = (const float*)d_in[11];
    float* out = (float*)d_out;

    // ---- workspace layout (256B aligned) ----
    char* ws = (char*)d_ws;
    size_t o = 0;
    auto take = [&](size_t bytes) { size_t r = o; o += (bytes + 255) & ~(size_t)255; return r; };
    size_t off_degi   = take((size_t)N_NODES * 4);
    size_t off_cursor = take((size_t)N_NODES * 4);
    size_t off_pooled = take((size_t)NGRAPH * HID * 4);
    size_t off_cnt    = take((size_t)NGRAPH * 4);
    size_t zero_bytes = o;                       // [0, o) gets memset to 0
    size_t off_dinv   = take((size_t)N_NODES * 4);
    size_t off_offs   = take((size_t)(N_NODES + 1) * 4);
    size_t off_part   = take((size_t)256 * 4);
    size_t off_csr    = take((size_t)N_EDGES * 4);
    size_t off_csrnm  = take((size_t)N_EDGES * 4);
    size_t off_hA     = take((size_t)N_NODES * HID * 4);
    size_t off_hB     = take((size_t)N_NODES * HID * 4);

    int*   degi   = (int*)(ws + off_degi);
    int*   cursor = (int*)(ws + off_cursor);
    float* pooled = (float*)(ws + off_pooled);
    float* cnt    = (float*)(ws + off_cnt);
    float* dinv   = (float*)(ws + off_dinv);
    int*   offs   = (int*)(ws + off_offs);
    int*   part   = (int*)(ws + off_part);
    int*   csr    = (int*)(ws + off_csr);
    float* csrnm  = (float*)(ws + off_csrnm);
    float* hA     = (float*)(ws + off_hA);
    float* hB     = (float*)(ws + off_hB);

    hipMemsetAsync(d_ws, 0, zero_bytes, stream);

    // degree + dinv + CSR build (amortized across 4 layers)
    k_deg<<<(N_EDGES + 255) / 256, 256, 0, stream>>>(ei, degi);
    k_dinv<<<(N_NODES + 255) / 256, 256, 0, stream>>>(degi, dinv);
    k_scan_part<<<SCAN_NB, 256, 0, stream>>>(degi, part);
    k_scan_mid<<<1, 256, 0, stream>>>(part);
    k_scan_final<<<SCAN_NB, 256, 0, stream>>>(degi, part, offs);
    k_fill<<<(N_EDGES + 255) / 256, 256, 0, stream>>>(ei, offs, dinv, cursor, csr, csrnm);

    // node embedding MLP: hB = relu(x@We1+be1); hA = hB@We2+be2
    k_embed1<<<(N_NODES + EM - 1) / EM, 256, 0, stream>>>(x, We1, be1, hB);
    int gemm_grid = (N_NODES + GM - 1) / GM;
    k_gemm<<<gemm_grid, 256, 0, stream>>>(hB, We2, be2, hA);

    // 4 GCN layers: hB = hA @ Wg[l];  hA = relu(agg(hB) + self + bias)
    for (int l = 0; l < NLAYERS; ++l) {
        k_gemm<<<gemm_grid, 256, 0, stream>>>(hA, Wg + (size_t)l * HID * HID, nullptr, hB);
        k_agg<<<(N_NODES + 3) / 4, 256, 0, stream>>>(hB, csr, csrnm, offs, dinv,
                                                     bg + (size_t)l * HID, hA);
    }

    // pooling + output head
    k_pool<<<(N_NODES + 8 * PN - 1) / (8 * PN), 256, 0, stream>>>(hA, bidx, pooled, cnt);
    k_out<<<NGRAPH, HID, 0, stream>>>(pooled, cnt, Wo, bo, out);
}